// Round 17
// baseline (4069.059 us; speedup 1.0000x reference)
//
#include <hip/hip_runtime.h>
#include <hip/hip_bf16.h>

#define EPSF 1e-5f

typedef unsigned short u16;
typedef unsigned int   u32;
typedef __attribute__((ext_vector_type(8))) short short8;
typedef __attribute__((ext_vector_type(4))) float f32x4;

constexpr int B  = 256;
constexpr int T  = 128;
constexpr int H  = 1024;
constexpr int INNER = 3 * H;   // 3072
constexpr int BT = B * T;      // 32768
constexpr int NZ = 2 * H;      // 2048

__device__ inline u16 f2bf(float v) {
    u32 u = __float_as_uint(v);
    return (u16)((u + 0x7fffu + ((u >> 16) & 1u)) >> 16);
}
__device__ inline float bf2f(u16 h) { return __uint_as_float(((u32)h) << 16); }

// async global->LDS, 16B per lane; LDS dest = wave-uniform base + lane*16
__device__ __forceinline__ void gload_lds16(const void* g, void* l) {
    __builtin_amdgcn_global_load_lds(
        (const __attribute__((address_space(1))) void*)g,
        (__attribute__((address_space(3))) void*)l,
        16, 0, 0);
}

// ---------- one-time: split fp32 array -> bf16 hi/lo planes (vectorized) ----------
__global__ __launch_bounds__(256)
void split_f32(const float* __restrict__ src, u16* __restrict__ dhi, u16* __restrict__ dlo)
{
    const size_t i = ((size_t)blockIdx.x * 256 + threadIdx.x) * 4;
    float4 v = *(const float4*)(src + i);
    u16 h0 = f2bf(v.x), h1 = f2bf(v.y), h2 = f2bf(v.z), h3 = f2bf(v.w);
    u16 l0 = f2bf(v.x - bf2f(h0)), l1 = f2bf(v.y - bf2f(h1));
    u16 l2 = f2bf(v.z - bf2f(h2)), l3 = f2bf(v.w - bf2f(h3));
    uint2 hp, lp;
    hp.x = (u32)h0 | ((u32)h1 << 16); hp.y = (u32)h2 | ((u32)h3 << 16);
    lp.x = (u32)l0 | ((u32)l1 << 16); lp.y = (u32)l2 | ((u32)l3 << 16);
    *(uint2*)(dhi + i) = hp;
    *(uint2*)(dlo + i) = lp;
}

// ---------- one-time: transpose fp32 [1024][3072] -> split bf16 [3072][1024] ----------
__global__ __launch_bounds__(256)
void transpose_split(const float* __restrict__ src, u16* __restrict__ dhi, u16* __restrict__ dlo)
{
    __shared__ float tile[32][33];
    const int tx = threadIdx.x & 31, ty = threadIdx.x >> 5;
    const int bx = blockIdx.x, by = blockIdx.y;
    #pragma unroll
    for (int i = 0; i < 4; ++i)
        tile[ty + i * 8][tx] = src[(size_t)(by * 32 + ty + i * 8) * INNER + bx * 32 + tx];
    __syncthreads();
    #pragma unroll
    for (int i = 0; i < 4; ++i) {
        int n = bx * 32 + ty + i * 8;
        int k = by * 32 + tx;
        float v = tile[tx][ty + i * 8];
        u16 hi = f2bf(v);
        dhi[(size_t)n * H + k] = hi;
        dlo[(size_t)n * H + k] = f2bf(v - bf2f(hi));
    }
}

// ---------- big GEMM via global_load_lds (pre-split A chunk), VALIDATED round-13 ----------
__global__ __launch_bounds__(256)
void gemm_s1gl(const u16* __restrict__ Ahi_, const u16* __restrict__ Alo_,
               const u16* __restrict__ Bhi, const u16* __restrict__ Blo,
               const float* __restrict__ bias, float* __restrict__ C)
{
    constexpr int BM = 128, BN = 128, FM = 4, FN = 4;
    __shared__ char lds[(BM + BN) * 256];   // 64 KB
    char* sAhi = lds;
    char* sAlo = lds + BM * 128;
    char* sBhi = lds + BM * 256;
    char* sBlo = lds + BM * 256 + BN * 128;

    const int tid = threadIdx.x;
    const int m0 = blockIdx.y * BM, n0 = blockIdx.x * BN;
    const int wid = tid >> 6, lane = tid & 63;
    const int wm = wid >> 1, wn = wid & 1;
    const int lr = lane & 15, kg = lane >> 4;

    const int jrow8 = lane >> 3;
    const int kcs   = (lane & 7) ^ jrow8;

    f32x4 acc[FM][FN] = {};

    for (int k0 = 0; k0 < H; k0 += 64) {
        #pragma unroll
        for (int i = 0; i < 4; ++i) {
            const int chunk = wid * 4 + i;
            const int row   = chunk * 8 + jrow8;
            const size_t goA = (size_t)(m0 + row) * H + k0 + kcs * 8;
            const size_t goB = (size_t)(n0 + row) * H + k0 + kcs * 8;
            gload_lds16(Ahi_ + goA, sAhi + chunk * 1024);
            gload_lds16(Alo_ + goA, sAlo + chunk * 1024);
            gload_lds16(Bhi  + goB, sBhi + chunk * 1024);
            gload_lds16(Blo  + goB, sBlo + chunk * 1024);
        }
        __syncthreads();

        #pragma unroll
        for (int ks = 0; ks < 2; ++ks) {
            short8 ah[FM], al[FM], bh[FN], bl[FN];
            #pragma unroll
            for (int mi = 0; mi < FM; ++mi) {
                int row = wm * FM * 16 + mi * 16 + lr;
                int off = row * 128 + ((((ks << 2) | kg) ^ (row & 7)) << 4);
                ah[mi] = *(const short8*)(sAhi + off);
                al[mi] = *(const short8*)(sAlo + off);
            }
            #pragma unroll
            for (int ni = 0; ni < FN; ++ni) {
                int row = wn * FN * 16 + ni * 16 + lr;
                int off = row * 128 + ((((ks << 2) | kg) ^ (row & 7)) << 4);
                bh[ni] = *(const short8*)(sBhi + off);
                bl[ni] = *(const short8*)(sBlo + off);
            }
            #pragma unroll
            for (int mi = 0; mi < FM; ++mi)
                #pragma unroll
                for (int ni = 0; ni < FN; ++ni) {
                    acc[mi][ni] = __builtin_amdgcn_mfma_f32_16x16x32_bf16(ah[mi], bh[ni], acc[mi][ni], 0, 0, 0);
                    acc[mi][ni] = __builtin_amdgcn_mfma_f32_16x16x32_bf16(ah[mi], bl[ni], acc[mi][ni], 0, 0, 0);
                    acc[mi][ni] = __builtin_amdgcn_mfma_f32_16x16x32_bf16(al[mi], bh[ni], acc[mi][ni], 0, 0, 0);
                }
        }
        __syncthreads();
    }

    #pragma unroll
    for (int ni = 0; ni < FN; ++ni) {
        int col = n0 + wn * FN * 16 + ni * 16 + lr;
        float bb = bias[col];
        #pragma unroll
        for (int mi = 0; mi < FM; ++mi) {
            #pragma unroll
            for (int r = 0; r < 4; ++r) {
                int row = m0 + wm * FM * 16 + mi * 16 + kg * 4 + r;
                C[(size_t)row * INNER + col] = acc[mi][ni][r] + bb;
            }
        }
    }
}

// ---------- big GEMM (inline-split A, validated round-11 fallback) ----------
__global__ __launch_bounds__(256)
void gemm_s1(const float* __restrict__ Af,
             const u16* __restrict__ Bhi, const u16* __restrict__ Blo,
             const float* __restrict__ bias, float* __restrict__ C)
{
    constexpr int BM = 128, BN = 128, FM = 4, FN = 4;
    __shared__ char lds[(BM + BN) * 256];
    char* sAhi = lds;
    char* sAlo = lds + BM * 128;
    char* sBhi = lds + BM * 256;
    char* sBlo = lds + BM * 256 + BN * 128;

    const int tid = threadIdx.x;
    const int m0 = blockIdx.y * BM, n0 = blockIdx.x * BN;
    const int wid = tid >> 6, lane = tid & 63;
    const int wm = wid >> 1, wn = wid & 1;
    const int lr = lane & 15, kg = lane >> 4;

    f32x4 acc[FM][FN] = {};

    for (int k0 = 0; k0 < H; k0 += 64) {
        {
            constexpr int NC = BM * 16 / 256;
            #pragma unroll
            for (int i = 0; i < NC; ++i) {
                int c = tid + i * 256;
                int row = c >> 4, kc = c & 15;
                const float4 v = *(const float4*)(Af + (size_t)(m0 + row) * H + k0 + kc * 4);
                u16 h0 = f2bf(v.x), h1 = f2bf(v.y), h2 = f2bf(v.z), h3 = f2bf(v.w);
                u16 l0 = f2bf(v.x - bf2f(h0)), l1 = f2bf(v.y - bf2f(h1));
                u16 l2 = f2bf(v.z - bf2f(h2)), l3 = f2bf(v.w - bf2f(h3));
                uint2 hp, lp;
                hp.x = (u32)h0 | ((u32)h1 << 16); hp.y = (u32)h2 | ((u32)h3 << 16);
                lp.x = (u32)l0 | ((u32)l1 << 16); lp.y = (u32)l2 | ((u32)l3 << 16);
                int boff = row * 128 + ((((kc >> 1)) ^ (row & 7)) << 4) + ((kc & 1) << 3);
                *(uint2*)(sAhi + boff) = hp;
                *(uint2*)(sAlo + boff) = lp;
            }
        }
        {
            constexpr int NC = BN * 8 / 256;
            #pragma unroll
            for (int i = 0; i < NC; ++i) {
                int c = tid + i * 256;
                int row = c >> 3, kc = c & 7;
                int boff = row * 128 + ((kc ^ (row & 7)) << 4);
                *(float4*)(sBhi + boff) = *(const float4*)(Bhi + (size_t)(n0 + row) * H + k0 + kc * 8);
                *(float4*)(sBlo + boff) = *(const float4*)(Blo + (size_t)(n0 + row) * H + k0 + kc * 8);
            }
        }
        __syncthreads();

        #pragma unroll
        for (int ks = 0; ks < 2; ++ks) {
            short8 ah[FM], al[FM], bh[FN], bl[FN];
            #pragma unroll
            for (int mi = 0; mi < FM; ++mi) {
                int row = wm * FM * 16 + mi * 16 + lr;
                int off = row * 128 + ((((ks << 2) | kg) ^ (row & 7)) << 4);
                ah[mi] = *(const short8*)(sAhi + off);
                al[mi] = *(const short8*)(sAlo + off);
            }
            #pragma unroll
            for (int ni = 0; ni < FN; ++ni) {
                int row = wn * FN * 16 + ni * 16 + lr;
                int off = row * 128 + ((((ks << 2) | kg) ^ (row & 7)) << 4);
                bh[ni] = *(const short8*)(sBhi + off);
                bl[ni] = *(const short8*)(sBlo + off);
            }
            #pragma unroll
            for (int mi = 0; mi < FM; ++mi)
                #pragma unroll
                for (int ni = 0; ni < FN; ++ni) {
                    acc[mi][ni] = __builtin_amdgcn_mfma_f32_16x16x32_bf16(ah[mi], bh[ni], acc[mi][ni], 0, 0, 0);
                    acc[mi][ni] = __builtin_amdgcn_mfma_f32_16x16x32_bf16(ah[mi], bl[ni], acc[mi][ni], 0, 0, 0);
                    acc[mi][ni] = __builtin_amdgcn_mfma_f32_16x16x32_bf16(al[mi], bh[ni], acc[mi][ni], 0, 0, 0);
                }
        }
        __syncthreads();
    }

    #pragma unroll
    for (int ni = 0; ni < FN; ++ni) {
        int col = n0 + wn * FN * 16 + ni * 16 + lr;
        float bb = bias[col];
        #pragma unroll
        for (int mi = 0; mi < FM; ++mi) {
            #pragma unroll
            for (int r = 0; r < 4; ++r) {
                int row = m0 + wm * FM * 16 + mi * 16 + kg * 4 + r;
                C[(size_t)row * INNER + col] = acc[mi][ni][r] + bb;
            }
        }
    }
}

// ---------- split-K step GEMM A (G1): 16x64 tiles, grid.z = k-half ----------
// 4 waves = 1m x 4n. LDS 40KB -> up to 4 blocks/CU. KSPAN=512 -> 4 k-iters.
__global__ __launch_bounds__(256)
void step_gemm_skA(const u16* __restrict__ Ahi, const u16* __restrict__ Alo,
                   const u16* __restrict__ Bhi, const u16* __restrict__ Blo,
                   float* __restrict__ Cpart, int ldc, int partStride)
{
    constexpr int BM = 16, BN = 64;
    constexpr int KSPAN = H / 2;   // 512
    __shared__ char lds[(BM + BN) * 512];   // 40 KB
    char* sAhi = lds;
    char* sAlo = lds + BM * 256;
    char* sBhi = lds + BM * 512;
    char* sBlo = lds + BM * 512 + BN * 256;

    const int tid = threadIdx.x;
    const int m0 = blockIdx.y * BM, n0 = blockIdx.x * BN;
    const int kbeg = blockIdx.z * KSPAN;
    const int wid = tid >> 6, lane = tid & 63;
    const int wn = wid;                      // NWM=1, NWN=4
    const int lr = lane & 15, kg = lane >> 4;

    const int lrow = lane >> 4;
    const int lslot = lane & 15;

    f32x4 acc = {};

    for (int k0 = kbeg; k0 < kbeg + KSPAN; k0 += 128) {
        {   // A: BM/16 = 1 chunk per wave
            const int c = wid;
            const int r = c * 4 + lrow;
            const int swz = lslot ^ (r & 7);
            const size_t go = (size_t)(m0 + r) * H + k0 + swz * 8;
            gload_lds16(Ahi + go, sAhi + c * 1024);
            gload_lds16(Alo + go, sAlo + c * 1024);
        }
        #pragma unroll
        for (int i = 0; i < BN / 16; ++i) {
            const int c = wid * (BN / 16) + i;
            const int r = c * 4 + lrow;
            const int swz = lslot ^ (r & 7);
            const size_t go = (size_t)(n0 + r) * H + k0 + swz * 8;
            gload_lds16(Bhi + go, sBhi + c * 1024);
            gload_lds16(Blo + go, sBlo + c * 1024);
        }
        __syncthreads();

        #pragma unroll
        for (int ks = 0; ks < 4; ++ks) {
            short8 ah, al, bh, bl;
            {
                int row = lr;
                int off = row * 256 + ((((ks << 2) | kg) ^ (row & 7)) << 4);
                ah = *(const short8*)(sAhi + off);
                al = *(const short8*)(sAlo + off);
            }
            {
                int row = wn * 16 + lr;
                int off = row * 256 + ((((ks << 2) | kg) ^ (row & 7)) << 4);
                bh = *(const short8*)(sBhi + off);
                bl = *(const short8*)(sBlo + off);
            }
            acc = __builtin_amdgcn_mfma_f32_16x16x32_bf16(ah, bh, acc, 0, 0, 0);
            acc = __builtin_amdgcn_mfma_f32_16x16x32_bf16(ah, bl, acc, 0, 0, 0);
            acc = __builtin_amdgcn_mfma_f32_16x16x32_bf16(al, bh, acc, 0, 0, 0);
        }
        __syncthreads();
    }

    float* Cp = Cpart + (size_t)blockIdx.z * partStride;
    const int col = n0 + wn * 16 + lr;
    #pragma unroll
    for (int r = 0; r < 4; ++r) {
        int row = m0 + kg * 4 + r;
        Cp[(size_t)row * ldc + col] = acc[r];
    }
}

// ---------- split-K step GEMM (G2): 32x32 tiles, grid.z = k-half (VALIDATED r16) ----------
__global__ __launch_bounds__(256)
void step_gemm_sk(const u16* __restrict__ Ahi, const u16* __restrict__ Alo,
                  const u16* __restrict__ Bhi, const u16* __restrict__ Blo,
                  float* __restrict__ Cpart, int ldc, int partStride)
{
    constexpr int BM = 32, BN = 32;
    constexpr int KSPAN = H / 2;   // 512
    __shared__ char lds[(BM + BN) * 512];
    char* sAhi = lds;
    char* sAlo = lds + BM * 256;
    char* sBhi = lds + BM * 512;
    char* sBlo = lds + BM * 512 + BN * 256;

    const int tid = threadIdx.x;
    const int m0 = blockIdx.y * BM, n0 = blockIdx.x * BN;
    const int kbeg = blockIdx.z * KSPAN;
    const int wid = tid >> 6, lane = tid & 63;
    const int wm = wid >> 1, wn = wid & 1;
    const int lr = lane & 15, kg = lane >> 4;

    const int lrow = lane >> 4;
    const int lslot = lane & 15;

    f32x4 acc = {};

    for (int k0 = kbeg; k0 < kbeg + KSPAN; k0 += 128) {
        #pragma unroll
        for (int i = 0; i < BM / 16; ++i) {
            const int c = wid * (BM / 16) + i;
            const int r = c * 4 + lrow;
            const int swz = lslot ^ (r & 7);
            const size_t go = (size_t)(m0 + r) * H + k0 + swz * 8;
            gload_lds16(Ahi + go, sAhi + c * 1024);
            gload_lds16(Alo + go, sAlo + c * 1024);
        }
        #pragma unroll
        for (int i = 0; i < BN / 16; ++i) {
            const int c = wid * (BN / 16) + i;
            const int r = c * 4 + lrow;
            const int swz = lslot ^ (r & 7);
            const size_t go = (size_t)(n0 + r) * H + k0 + swz * 8;
            gload_lds16(Bhi + go, sBhi + c * 1024);
            gload_lds16(Blo + go, sBlo + c * 1024);
        }
        __syncthreads();

        #pragma unroll
        for (int ks = 0; ks < 4; ++ks) {
            short8 ah, al, bh, bl;
            {
                int row = wm * 16 + lr;
                int off = row * 256 + ((((ks << 2) | kg) ^ (row & 7)) << 4);
                ah = *(const short8*)(sAhi + off);
                al = *(const short8*)(sAlo + off);
            }
            {
                int row = wn * 16 + lr;
                int off = row * 256 + ((((ks << 2) | kg) ^ (row & 7)) << 4);
                bh = *(const short8*)(sBhi + off);
                bl = *(const short8*)(sBlo + off);
            }
            acc = __builtin_amdgcn_mfma_f32_16x16x32_bf16(ah, bh, acc, 0, 0, 0);
            acc = __builtin_amdgcn_mfma_f32_16x16x32_bf16(ah, bl, acc, 0, 0, 0);
            acc = __builtin_amdgcn_mfma_f32_16x16x32_bf16(al, bh, acc, 0, 0, 0);
        }
        __syncthreads();
    }

    float* Cp = Cpart + (size_t)blockIdx.z * partStride;
    const int col = n0 + wn * 16 + lr;
    #pragma unroll
    for (int r = 0; r < 4; ++r) {
        int row = m0 + wm * 16 + kg * 4 + r;
        Cp[(size_t)row * ldc + col] = acc[r];
    }
}

// ---------- block reduce (sum, sumsq) over 256 threads ----------
__device__ inline void block_reduce2(float& s, float& sq, int tid) {
    #pragma unroll
    for (int off = 32; off > 0; off >>= 1) { s += __shfl_down(s, off); sq += __shfl_down(sq, off); }
    __shared__ float rs[4], rq[4];
    if ((tid & 63) == 0) { rs[tid >> 6] = s; rq[tid >> 6] = sq; }
    __syncthreads();
    s  = rs[0] + rs[1] + rs[2] + rs[3];
    sq = rq[0] + rq[1] + rq[2] + rq[3];
    __syncthreads();
}

// ---------- per-row LN stats over S1b rows of 3072 -> (mean, 1/denom) ----------
__global__ __launch_bounds__(256)
void ln_stats_v(const float* __restrict__ S1b, float* __restrict__ stat)
{
    const int row = blockIdx.x, tid = threadIdx.x;
    const float* p = S1b + (size_t)row * INNER;
    float s = 0.f, sq = 0.f;
    #pragma unroll
    for (int i = 0; i < 3; ++i) {
        float4 v = *(const float4*)(p + (tid + i * 256) * 4);
        s += v.x + v.y + v.z + v.w;
        sq += v.x*v.x + v.y*v.y + v.z*v.z + v.w*v.w;
    }
    block_reduce2(s, sq, tid);
    if (tid == 0) {
        float mean = s / (float)INNER;
        float var  = sq / (float)INNER - mean * mean;
        stat[row * 2 + 0] = mean;
        stat[row * 2 + 1] = 1.f / (sqrtf(var + EPSF) + EPSF);
    }
}

// ---------- step elementwise 1 (sums 2 split-K partials of s2) ----------
__global__ __launch_bounds__(256)
void step_e1_v(const float* __restrict__ s2p0, const float* __restrict__ s2p1,
               const float* __restrict__ S1b,
               const float* __restrict__ stat, const float* __restrict__ h,
               const float* __restrict__ gammas, const float* __restrict__ betas,
               float* __restrict__ z, u16* __restrict__ rh_hi, u16* __restrict__ rh_lo, int t)
{
    const int b = blockIdx.x, tid = threadIdx.x;
    float az[4], ar[4];
    {
        float4 vz0 = *(const float4*)(s2p0 + (size_t)b * NZ + tid * 4);
        float4 vz1 = *(const float4*)(s2p1 + (size_t)b * NZ + tid * 4);
        float4 vr0 = *(const float4*)(s2p0 + (size_t)b * NZ + 1024 + tid * 4);
        float4 vr1 = *(const float4*)(s2p1 + (size_t)b * NZ + 1024 + tid * 4);
        az[0]=vz0.x+vz1.x; az[1]=vz0.y+vz1.y; az[2]=vz0.z+vz1.z; az[3]=vz0.w+vz1.w;
        ar[0]=vr0.x+vr1.x; ar[1]=vr0.y+vr1.y; ar[2]=vr0.z+vr1.z; ar[3]=vr0.w+vr1.w;
    }
    float s = 0.f, sq = 0.f;
    #pragma unroll
    for (int q = 0; q < 4; ++q) { s += az[q] + ar[q]; sq += az[q]*az[q] + ar[q]*ar[q]; }
    block_reduce2(s, sq, tid);
    const float mean = s / (float)NZ;
    const float var  = sq / (float)NZ - mean * mean;
    const float denom = sqrtf(var + EPSF) + EPSF;

    const size_t srow = (size_t)b * T + t;
    const float s1m = stat[srow * 2 + 0], s1r = stat[srow * 2 + 1];
    const float* s1 = S1b + srow * INNER;
    const int j0 = tid * 4;
    float4 zo;
    float* zp = (float*)&zo;
    #pragma unroll
    for (int q = 0; q < 4; ++q) {
        int j = j0 + q;
        float s1v = gammas[j] * (s1[j] - s1m) * s1r + betas[j];
        float ln  = gammas[INNER + j] * (az[q] - mean) / denom + betas[INNER + j];
        float sv  = 0.2f * (s1v + ln) + 0.5f;
        zp[q] = fminf(fmaxf(sv, 0.f), 1.f);
    }
    *(float4*)(z + (size_t)b * H + j0) = zo;

    uint2 hp, lp;
    u16 hh[4], ll[4];
    #pragma unroll
    for (int q = 0; q < 4; ++q) {
        int j = 1024 + j0 + q;
        float s1v = gammas[j] * (s1[j] - s1m) * s1r + betas[j];
        float ln  = gammas[INNER + j] * (ar[q] - mean) / denom + betas[INNER + j];
        float sv  = 0.2f * (s1v + ln) + 0.5f;
        sv = fminf(fmaxf(sv, 0.f), 1.f);
        float rv = sv * h[(size_t)b * H + j0 + q];
        hh[q] = f2bf(rv);
        ll[q] = f2bf(rv - bf2f(hh[q]));
    }
    hp.x = (u32)hh[0] | ((u32)hh[1] << 16); hp.y = (u32)hh[2] | ((u32)hh[3] << 16);
    lp.x = (u32)ll[0] | ((u32)ll[1] << 16); lp.y = (u32)ll[2] | ((u32)ll[3] << 16);
    *(uint2*)(rh_hi + (size_t)b * H + j0) = hp;
    *(uint2*)(rh_lo + (size_t)b * H + j0) = lp;
}

// ---------- step elementwise 2 (sums 2 split-K partials of candraw) ----------
__global__ __launch_bounds__(256)
void step_e2_v(const float* __restrict__ cand0, const float* __restrict__ cand1,
               const float* __restrict__ S1b, const float* __restrict__ stat,
               const float* __restrict__ gammas, const float* __restrict__ betas,
               const float* __restrict__ z, float* __restrict__ h,
               u16* __restrict__ h_hi, u16* __restrict__ h_lo,
               float* __restrict__ out, int t)
{
    const int b = blockIdx.x, tid = threadIdx.x;
    float a[4];
    {
        float4 v0 = *(const float4*)(cand0 + (size_t)b * H + tid * 4);
        float4 v1 = *(const float4*)(cand1 + (size_t)b * H + tid * 4);
        a[0]=v0.x+v1.x; a[1]=v0.y+v1.y; a[2]=v0.z+v1.z; a[3]=v0.w+v1.w;
    }
    float s = a[0]+a[1]+a[2]+a[3];
    float sq = a[0]*a[0]+a[1]*a[1]+a[2]*a[2]+a[3]*a[3];
    block_reduce2(s, sq, tid);
    const float mean = s / (float)H;
    const float var  = sq / (float)H - mean * mean;
    const float denom = sqrtf(var + EPSF) + EPSF;

    const size_t srow = (size_t)b * T + t;
    const float s1m = stat[srow * 2 + 0], s1r = stat[srow * 2 + 1];
    const float* s1 = S1b + srow * INNER + NZ;
    const int j0 = tid * 4;
    float4 ho;
    float* hp_ = (float*)&ho;
    u16 hh[4], ll[4];
    #pragma unroll
    for (int q = 0; q < 4; ++q) {
        int j = j0 + q;
        float s1v = gammas[NZ + j] * (s1[j] - s1m) * s1r + betas[NZ + j];
        float ln  = gammas[INNER + NZ + j] * (a[q] - mean) / denom + betas[INNER + NZ + j];
        float cand = tanhf(s1v + ln);
        float zz = z[(size_t)b * H + j];
        float hold = h[(size_t)b * H + j];
        float hn = zz * hold + (1.f - zz) * cand;
        hp_[q] = hn;
        hh[q] = f2bf(hn);
        ll[q] = f2bf(hn - bf2f(hh[q]));
    }
    *(float4*)(h + (size_t)b * H + j0) = ho;
    uint2 hpck, lpck;
    hpck.x = (u32)hh[0] | ((u32)hh[1] << 16); hpck.y = (u32)hh[2] | ((u32)hh[3] << 16);
    lpck.x = (u32)ll[0] | ((u32)ll[1] << 16); lpck.y = (u32)ll[2] | ((u32)ll[3] << 16);
    *(uint2*)(h_hi + (size_t)b * H + j0) = hpck;
    *(uint2*)(h_lo + (size_t)b * H + j0) = lpck;
    *(float4*)(out + ((size_t)b * T + t) * H + j0) = ho;
}

// ================= fallback (validated fp32 path) =================
__global__ __launch_bounds__(256)
void ln_rows_v(float* __restrict__ S1, const float* __restrict__ bias,
               const float* __restrict__ gammas, const float* __restrict__ betas)
{
    const int row = blockIdx.x, tid = threadIdx.x;
    float* p = S1 + (size_t)row * INNER;
    float a[12];
    float s = 0.f, sq = 0.f;
    #pragma unroll
    for (int i = 0; i < 3; ++i) {
        int c = tid + i * 256;
        float4 v = *(const float4*)(p + c * 4);
        float4 bb = *(const float4*)(bias + c * 4);
        a[i*4+0] = v.x + bb.x; a[i*4+1] = v.y + bb.y; a[i*4+2] = v.z + bb.z; a[i*4+3] = v.w + bb.w;
        s += a[i*4+0] + a[i*4+1] + a[i*4+2] + a[i*4+3];
        sq += a[i*4+0]*a[i*4+0] + a[i*4+1]*a[i*4+1] + a[i*4+2]*a[i*4+2] + a[i*4+3]*a[i*4+3];
    }
    block_reduce2(s, sq, tid);
    const float mean = s / (float)INNER;
    const float var  = sq / (float)INNER - mean * mean;
    const float denom = sqrtf(var + EPSF) + EPSF;
    #pragma unroll
    for (int i = 0; i < 3; ++i) {
        int c = tid + i * 256;
        float4 o;
        o.x = gammas[c*4+0] * (a[i*4+0] - mean) / denom + betas[c*4+0];
        o.y = gammas[c*4+1] * (a[i*4+1] - mean) / denom + betas[c*4+1];
        o.z = gammas[c*4+2] * (a[i*4+2] - mean) / denom + betas[c*4+2];
        o.w = gammas[c*4+3] * (a[i*4+3] - mean) / denom + betas[c*4+3];
        *(float4*)(p + c * 4) = o;
    }
}

__global__ __launch_bounds__(256)
void gemm_fb(const float* __restrict__ A, int lda,
             const float* __restrict__ Bm, int ldb,
             float* __restrict__ C, int ldc, int K)
{
    constexpr int BM = 64, BN = 64, BK = 16;
    __shared__ float As[BK][BM];
    __shared__ float Bs[BK][BN];
    const int tid = threadIdx.x;
    const int tx = tid & 15, ty = tid >> 4;
    float acc[4][4] = {};
    const float* Ab = A + (size_t)blockIdx.y * BM * lda;
    const float* Bb = Bm + (size_t)blockIdx.x * BN;
    for (int k0 = 0; k0 < K; k0 += BK) {
        #pragma unroll
        for (int i = 0; i < 4; ++i) {
            int e = tid + i * 256; int m = e >> 4, k = e & 15;
            As[k][m] = Ab[(size_t)m * lda + k0 + k];
        }
        #pragma unroll
        for (int i = 0; i < 4; ++i) {
            int e = tid + i * 256; int k = e >> 6, n = e & 63;
            Bs[k][n] = Bb[(size_t)(k0 + k) * ldb + n];
        }
        __syncthreads();
        #pragma unroll
        for (int k = 0; k < BK; ++k) {
            float av[4], bv[4];
            #pragma unroll
            for (int i = 0; i < 4; ++i) av[i] = As[k][ty * 4 + i];
            #pragma unroll
            for (int j = 0; j < 4; ++j) bv[j] = Bs[k][tx * 4 + j];
            #pragma unroll
            for (int i = 0; i < 4; ++i)
                #pragma unroll
                for (int j = 0; j < 4; ++j)
                    acc[i][j] = fmaf(av[i], bv[j], acc[i][j]);
        }
        __syncthreads();
    }
    const int row0 = blockIdx.y * BM + ty * 4;
    const int col0 = blockIdx.x * BN + tx * 4;
    #pragma unroll
    for (int i = 0; i < 4; ++i)
        #pragma unroll
        for (int j = 0; j < 4; ++j)
            C[(size_t)(row0 + i) * ldc + col0 + j] = acc[i][j];
}

__global__ __launch_bounds__(256)
void step_e1_fb(const float* __restrict__ s2raw, const float* __restrict__ S1,
                const float* __restrict__ h,
                const float* __restrict__ gammas, const float* __restrict__ betas,
                float* __restrict__ z, float* __restrict__ rh, int t)
{
    const int b = blockIdx.x, tid = threadIdx.x;
    const float* row = s2raw + (size_t)b * NZ;
    float v[8]; float s = 0.f, sq = 0.f;
    #pragma unroll
    for (int i = 0; i < 8; ++i) { v[i] = row[tid + i * 256]; s += v[i]; sq += v[i]*v[i]; }
    block_reduce2(s, sq, tid);
    const float mean = s / (float)NZ;
    const float var  = sq / (float)NZ - mean * mean;
    const float denom = sqrtf(var + EPSF) + EPSF;
    const float* s1 = S1 + (size_t)(b * T + t) * INNER;
    #pragma unroll
    for (int i = 0; i < 8; ++i) {
        int j = tid + i * 256;
        float ln = gammas[INNER + j] * (v[i] - mean) / denom + betas[INNER + j];
        float sv = 0.2f * (s1[j] + ln) + 0.5f;
        sv = fminf(fmaxf(sv, 0.f), 1.f);
        if (j < H) z[(size_t)b * H + j] = sv;
        else       rh[(size_t)b * H + (j - H)] = sv * h[(size_t)b * H + (j - H)];
    }
}

__global__ __launch_bounds__(256)
void step_e2_fb(const float* __restrict__ candraw, const float* __restrict__ S1,
                const float* __restrict__ gammas, const float* __restrict__ betas,
                const float* __restrict__ z, float* __restrict__ h,
                float* __restrict__ out, int t)
{
    const int b = blockIdx.x, tid = threadIdx.x;
    float v[4]; float s = 0.f, sq = 0.f;
    #pragma unroll
    for (int i = 0; i < 4; ++i) { v[i] = candraw[(size_t)b * H + tid + i * 256]; s += v[i]; sq += v[i]*v[i]; }
    block_reduce2(s, sq, tid);
    const float mean = s / (float)H;
    const float var  = sq / (float)H - mean * mean;
    const float denom = sqrtf(var + EPSF) + EPSF;
    const float* s1 = S1 + (size_t)(b * T + t) * INNER + NZ;
    #pragma unroll
    for (int i = 0; i < 4; ++i) {
        int j = tid + i * 256;
        float ln = gammas[INNER + NZ + j] * (v[i] - mean) / denom + betas[INNER + NZ + j];
        float cand = tanhf(s1[j] + ln);
        float zz = z[(size_t)b * H + j];
        float hold = h[(size_t)b * H + j];
        float hn = zz * hold + (1.f - zz) * cand;
        h[(size_t)b * H + j] = hn;
        out[((size_t)b * T + t) * H + j] = hn;
    }
}

// ================= launch =================
extern "C" void kernel_launch(void* const* d_in, const int* in_sizes, int n_in,
                              void* d_out, int out_size, void* d_ws, size_t ws_size,
                              hipStream_t stream) {
    const float* x      = (const float*)d_in[0];
    const float* W      = (const float*)d_in[1];
    const float* U      = (const float*)d_in[2];
    const float* bias   = (const float*)d_in[3];
    const float* gammas = (const float*)d_in[4];
    const float* betas  = (const float*)d_in[5];
    float* out = (float*)d_out;
    (void)in_sizes; (void)n_in; (void)out_size;

    char* ws = (char*)d_ws;
    size_t off = 0;
    auto alloc = [&](size_t bytes) { void* p = ws + off; off += (bytes + 255) & ~(size_t)255; return p; };

    const size_t sz_S1 = (size_t)BT * INNER * 4;          // 402.7 MB
    const size_t sz_T  = (size_t)INNER * H * 2;           // 6.29 MB per split half
    const size_t sz_st = (size_t)BT * 2 * 4;              // 256 KB
    constexpr int CHUNK = 8192;
    const size_t sz_xc = (size_t)CHUNK * H * 2;           // 16 MB per split half
    const size_t sz_small = ((size_t)B * H * 4) * 4 + (size_t)B * NZ * 4 * 2
                          + ((size_t)B * H * 2) * 4 + 16 * 1024;
    const size_t need_r9 = sz_S1 + 4 * sz_T + sz_st + sz_small;   // ~438.5 MB
    const size_t need_gl = need_r9 + 2 * sz_xc;                   // ~470.5 MB

    if (ws_size >= need_r9) {
        float* S1b   = (float*)alloc(sz_S1);
        u16* WT_hi   = (u16*)alloc(sz_T);
        u16* WT_lo   = (u16*)alloc(sz_T);
        u16* UT_hi   = (u16*)alloc(sz_T);
        u16* UT_lo   = (u16*)alloc(sz_T);
        float* stat  = (float*)alloc(sz_st);
        float* h     = (float*)alloc((size_t)B * H * 4);
        float* z     = (float*)alloc((size_t)B * H * 4);
        float* s2p2  = (float*)alloc((size_t)B * NZ * 4 * 2);  // 2 split-K partials (G1)
        float* cand2 = (float*)alloc((size_t)B * H * 4 * 2);   // 2 split-K partials (G2)
        u16* h_hi    = (u16*)alloc((size_t)B * H * 2);
        u16* h_lo    = (u16*)alloc((size_t)B * H * 2);
        u16* rh_hi   = (u16*)alloc((size_t)B * H * 2);
        u16* rh_lo   = (u16*)alloc((size_t)B * H * 2);

        transpose_split<<<dim3(INNER / 32, H / 32), 256, 0, stream>>>(W, WT_hi, WT_lo);
        transpose_split<<<dim3(INNER / 32, H / 32), 256, 0, stream>>>(U, UT_hi, UT_lo);

        if (ws_size >= need_gl) {
            u16* x_hi = (u16*)alloc(sz_xc);
            u16* x_lo = (u16*)alloc(sz_xc);
            for (int c0 = 0; c0 < BT; c0 += CHUNK) {
                split_f32<<<(CHUNK * H / 4) / 256, 256, 0, stream>>>(
                    x + (size_t)c0 * H, x_hi, x_lo);
                gemm_s1gl<<<dim3(INNER / 128, CHUNK / 128), 256, 0, stream>>>(
                    x_hi, x_lo, WT_hi, WT_lo, bias, S1b + (size_t)c0 * INNER);
            }
        } else {
            gemm_s1<<<dim3(INNER / 128, BT / 128), 256, 0, stream>>>(x, WT_hi, WT_lo, bias, S1b);
        }
        ln_stats_v<<<BT, 256, 0, stream>>>(S1b, stat);

        hipMemsetAsync(h,    0, (size_t)B * H * 4, stream);
        hipMemsetAsync(h_hi, 0, (size_t)B * H * 2, stream);
        hipMemsetAsync(h_lo, 0, (size_t)B * H * 2, stream);

        const u16* Uc_hi = UT_hi + (size_t)NZ * H;
        const u16* Uc_lo = UT_lo + (size_t)NZ * H;

        for (int t = 0; t < T; ++t) {
            // G1: 16x64 tiles, split-K=2 -> 1024 blocks (4 k-iters/block)
            step_gemm_skA<<<dim3(NZ / 64, B / 16, 2), 256, 0, stream>>>(
                h_hi, h_lo, UT_hi, UT_lo, s2p2, NZ, B * NZ);
            step_e1_v<<<B, 256, 0, stream>>>(s2p2, s2p2 + (size_t)B * NZ, S1b, stat,
                                             h, gammas, betas, z, rh_hi, rh_lo, t);
            // G2: 32x32 tiles, split-K=2 -> 512 blocks (validated round-16)
            step_gemm_sk<<<dim3(H / 32, B / 32, 2), 256, 0, stream>>>(
                rh_hi, rh_lo, Uc_hi, Uc_lo, cand2, H, B * H);
            step_e2_v<<<B, 256, 0, stream>>>(cand2, cand2 + (size_t)B * H, S1b, stat,
                                             gammas, betas, z, h, h_hi, h_lo, out, t);
        }
    } else {
        // fallback: validated fp32 path
        float* S1    = (float*)alloc(sz_S1);
        float* h     = (float*)alloc((size_t)B * H * 4);
        float* z     = (float*)alloc((size_t)B * H * 4);
        float* rh    = (float*)alloc((size_t)B * H * 4);
        float* s2raw = (float*)alloc((size_t)B * NZ * 4);
        float* candraw = (float*)alloc((size_t)B * H * 4);

        hipMemsetAsync(h, 0, (size_t)B * H * 4, stream);
        gemm_fb<<<dim3(INNER / 64, BT / 64), 256, 0, stream>>>(x, H, W, INNER, S1, INNER, H);
        ln_rows_v<<<BT, 256, 0, stream>>>(S1, bias, gammas, betas);
        for (int t = 0; t < T; ++t) {
            gemm_fb<<<dim3(NZ / 64, B / 64), 256, 0, stream>>>(h, H, U, INNER, s2raw, NZ, H);
            step_e1_fb<<<B, 256, 0, stream>>>(s2raw, S1, h, gammas, betas, z, rh, t);
            gemm_fb<<<dim3(H / 64, B / 64), 256, 0, stream>>>(rh, H, U + NZ, INNER, candraw, H, H);
            step_e2_fb<<<B, 256, 0, stream>>>(candraw, S1, gammas, betas, z, h, out, t);
        }
    }
}

// Round 18
// 4001.326 us; speedup vs baseline: 1.0169x; 1.0169x over previous
//
#include <hip/hip_runtime.h>
#include <hip/hip_bf16.h>

#define EPSF 1e-5f

typedef unsigned short u16;
typedef unsigned int   u32;
typedef __attribute__((ext_vector_type(8))) short short8;
typedef __attribute__((ext_vector_type(4))) float f32x4;

constexpr int B  = 256;
constexpr int T  = 128;
constexpr int H  = 1024;
constexpr int INNER = 3 * H;   // 3072
constexpr int BT = B * T;      // 32768
constexpr int NZ = 2 * H;      // 2048

__device__ inline u16 f2bf(float v) {
    u32 u = __float_as_uint(v);
    return (u16)((u + 0x7fffu + ((u >> 16) & 1u)) >> 16);
}
__device__ inline float bf2f(u16 h) { return __uint_as_float(((u32)h) << 16); }

// async global->LDS, 16B per lane; LDS dest = wave-uniform base + lane*16
__device__ __forceinline__ void gload_lds16(const void* g, void* l) {
    __builtin_amdgcn_global_load_lds(
        (const __attribute__((address_space(1))) void*)g,
        (__attribute__((address_space(3))) void*)l,
        16, 0, 0);
}

// ---------- one-time: split fp32 array -> bf16 hi/lo planes (vectorized) ----------
__global__ __launch_bounds__(256)
void split_f32(const float* __restrict__ src, u16* __restrict__ dhi, u16* __restrict__ dlo)
{
    const size_t i = ((size_t)blockIdx.x * 256 + threadIdx.x) * 4;
    float4 v = *(const float4*)(src + i);
    u16 h0 = f2bf(v.x), h1 = f2bf(v.y), h2 = f2bf(v.z), h3 = f2bf(v.w);
    u16 l0 = f2bf(v.x - bf2f(h0)), l1 = f2bf(v.y - bf2f(h1));
    u16 l2 = f2bf(v.z - bf2f(h2)), l3 = f2bf(v.w - bf2f(h3));
    uint2 hp, lp;
    hp.x = (u32)h0 | ((u32)h1 << 16); hp.y = (u32)h2 | ((u32)h3 << 16);
    lp.x = (u32)l0 | ((u32)l1 << 16); lp.y = (u32)l2 | ((u32)l3 << 16);
    *(uint2*)(dhi + i) = hp;
    *(uint2*)(dlo + i) = lp;
}

// ---------- one-time: transpose fp32 [1024][3072] -> split bf16 [3072][1024] ----------
__global__ __launch_bounds__(256)
void transpose_split(const float* __restrict__ src, u16* __restrict__ dhi, u16* __restrict__ dlo)
{
    __shared__ float tile[32][33];
    const int tx = threadIdx.x & 31, ty = threadIdx.x >> 5;
    const int bx = blockIdx.x, by = blockIdx.y;
    #pragma unroll
    for (int i = 0; i < 4; ++i)
        tile[ty + i * 8][tx] = src[(size_t)(by * 32 + ty + i * 8) * INNER + bx * 32 + tx];
    __syncthreads();
    #pragma unroll
    for (int i = 0; i < 4; ++i) {
        int n = bx * 32 + ty + i * 8;
        int k = by * 32 + tx;
        float v = tile[tx][ty + i * 8];
        u16 hi = f2bf(v);
        dhi[(size_t)n * H + k] = hi;
        dlo[(size_t)n * H + k] = f2bf(v - bf2f(hi));
    }
}

// ---------- big GEMM via global_load_lds (pre-split A chunk), VALIDATED round-13 ----------
__global__ __launch_bounds__(256)
void gemm_s1gl(const u16* __restrict__ Ahi_, const u16* __restrict__ Alo_,
               const u16* __restrict__ Bhi, const u16* __restrict__ Blo,
               const float* __restrict__ bias, float* __restrict__ C)
{
    constexpr int BM = 128, BN = 128, FM = 4, FN = 4;
    __shared__ char lds[(BM + BN) * 256];   // 64 KB
    char* sAhi = lds;
    char* sAlo = lds + BM * 128;
    char* sBhi = lds + BM * 256;
    char* sBlo = lds + BM * 256 + BN * 128;

    const int tid = threadIdx.x;
    const int m0 = blockIdx.y * BM, n0 = blockIdx.x * BN;
    const int wid = tid >> 6, lane = tid & 63;
    const int wm = wid >> 1, wn = wid & 1;
    const int lr = lane & 15, kg = lane >> 4;

    const int jrow8 = lane >> 3;
    const int kcs   = (lane & 7) ^ jrow8;

    f32x4 acc[FM][FN] = {};

    for (int k0 = 0; k0 < H; k0 += 64) {
        #pragma unroll
        for (int i = 0; i < 4; ++i) {
            const int chunk = wid * 4 + i;
            const int row   = chunk * 8 + jrow8;
            const size_t goA = (size_t)(m0 + row) * H + k0 + kcs * 8;
            const size_t goB = (size_t)(n0 + row) * H + k0 + kcs * 8;
            gload_lds16(Ahi_ + goA, sAhi + chunk * 1024);
            gload_lds16(Alo_ + goA, sAlo + chunk * 1024);
            gload_lds16(Bhi  + goB, sBhi + chunk * 1024);
            gload_lds16(Blo  + goB, sBlo + chunk * 1024);
        }
        __syncthreads();

        #pragma unroll
        for (int ks = 0; ks < 2; ++ks) {
            short8 ah[FM], al[FM], bh[FN], bl[FN];
            #pragma unroll
            for (int mi = 0; mi < FM; ++mi) {
                int row = wm * FM * 16 + mi * 16 + lr;
                int off = row * 128 + ((((ks << 2) | kg) ^ (row & 7)) << 4);
                ah[mi] = *(const short8*)(sAhi + off);
                al[mi] = *(const short8*)(sAlo + off);
            }
            #pragma unroll
            for (int ni = 0; ni < FN; ++ni) {
                int row = wn * FN * 16 + ni * 16 + lr;
                int off = row * 128 + ((((ks << 2) | kg) ^ (row & 7)) << 4);
                bh[ni] = *(const short8*)(sBhi + off);
                bl[ni] = *(const short8*)(sBlo + off);
            }
            #pragma unroll
            for (int mi = 0; mi < FM; ++mi)
                #pragma unroll
                for (int ni = 0; ni < FN; ++ni) {
                    acc[mi][ni] = __builtin_amdgcn_mfma_f32_16x16x32_bf16(ah[mi], bh[ni], acc[mi][ni], 0, 0, 0);
                    acc[mi][ni] = __builtin_amdgcn_mfma_f32_16x16x32_bf16(ah[mi], bl[ni], acc[mi][ni], 0, 0, 0);
                    acc[mi][ni] = __builtin_amdgcn_mfma_f32_16x16x32_bf16(al[mi], bh[ni], acc[mi][ni], 0, 0, 0);
                }
        }
        __syncthreads();
    }

    #pragma unroll
    for (int ni = 0; ni < FN; ++ni) {
        int col = n0 + wn * FN * 16 + ni * 16 + lr;
        float bb = bias[col];
        #pragma unroll
        for (int mi = 0; mi < FM; ++mi) {
            #pragma unroll
            for (int r = 0; r < 4; ++r) {
                int row = m0 + wm * FM * 16 + mi * 16 + kg * 4 + r;
                C[(size_t)row * INNER + col] = acc[mi][ni][r] + bb;
            }
        }
    }
}

// ---------- big GEMM (inline-split A, validated round-11 fallback) ----------
__global__ __launch_bounds__(256)
void gemm_s1(const float* __restrict__ Af,
             const u16* __restrict__ Bhi, const u16* __restrict__ Blo,
             const float* __restrict__ bias, float* __restrict__ C)
{
    constexpr int BM = 128, BN = 128, FM = 4, FN = 4;
    __shared__ char lds[(BM + BN) * 256];
    char* sAhi = lds;
    char* sAlo = lds + BM * 128;
    char* sBhi = lds + BM * 256;
    char* sBlo = lds + BM * 256 + BN * 128;

    const int tid = threadIdx.x;
    const int m0 = blockIdx.y * BM, n0 = blockIdx.x * BN;
    const int wid = tid >> 6, lane = tid & 63;
    const int wm = wid >> 1, wn = wid & 1;
    const int lr = lane & 15, kg = lane >> 4;

    f32x4 acc[FM][FN] = {};

    for (int k0 = 0; k0 < H; k0 += 64) {
        {
            constexpr int NC = BM * 16 / 256;
            #pragma unroll
            for (int i = 0; i < NC; ++i) {
                int c = tid + i * 256;
                int row = c >> 4, kc = c & 15;
                const float4 v = *(const float4*)(Af + (size_t)(m0 + row) * H + k0 + kc * 4);
                u16 h0 = f2bf(v.x), h1 = f2bf(v.y), h2 = f2bf(v.z), h3 = f2bf(v.w);
                u16 l0 = f2bf(v.x - bf2f(h0)), l1 = f2bf(v.y - bf2f(h1));
                u16 l2 = f2bf(v.z - bf2f(h2)), l3 = f2bf(v.w - bf2f(h3));
                uint2 hp, lp;
                hp.x = (u32)h0 | ((u32)h1 << 16); hp.y = (u32)h2 | ((u32)h3 << 16);
                lp.x = (u32)l0 | ((u32)l1 << 16); lp.y = (u32)l2 | ((u32)l3 << 16);
                int boff = row * 128 + ((((kc >> 1)) ^ (row & 7)) << 4) + ((kc & 1) << 3);
                *(uint2*)(sAhi + boff) = hp;
                *(uint2*)(sAlo + boff) = lp;
            }
        }
        {
            constexpr int NC = BN * 8 / 256;
            #pragma unroll
            for (int i = 0; i < NC; ++i) {
                int c = tid + i * 256;
                int row = c >> 3, kc = c & 7;
                int boff = row * 128 + ((kc ^ (row & 7)) << 4);
                *(float4*)(sBhi + boff) = *(const float4*)(Bhi + (size_t)(n0 + row) * H + k0 + kc * 8);
                *(float4*)(sBlo + boff) = *(const float4*)(Blo + (size_t)(n0 + row) * H + k0 + kc * 8);
            }
        }
        __syncthreads();

        #pragma unroll
        for (int ks = 0; ks < 2; ++ks) {
            short8 ah[FM], al[FM], bh[FN], bl[FN];
            #pragma unroll
            for (int mi = 0; mi < FM; ++mi) {
                int row = wm * FM * 16 + mi * 16 + lr;
                int off = row * 128 + ((((ks << 2) | kg) ^ (row & 7)) << 4);
                ah[mi] = *(const short8*)(sAhi + off);
                al[mi] = *(const short8*)(sAlo + off);
            }
            #pragma unroll
            for (int ni = 0; ni < FN; ++ni) {
                int row = wn * FN * 16 + ni * 16 + lr;
                int off = row * 128 + ((((ks << 2) | kg) ^ (row & 7)) << 4);
                bh[ni] = *(const short8*)(sBhi + off);
                bl[ni] = *(const short8*)(sBlo + off);
            }
            #pragma unroll
            for (int mi = 0; mi < FM; ++mi)
                #pragma unroll
                for (int ni = 0; ni < FN; ++ni) {
                    acc[mi][ni] = __builtin_amdgcn_mfma_f32_16x16x32_bf16(ah[mi], bh[ni], acc[mi][ni], 0, 0, 0);
                    acc[mi][ni] = __builtin_amdgcn_mfma_f32_16x16x32_bf16(ah[mi], bl[ni], acc[mi][ni], 0, 0, 0);
                    acc[mi][ni] = __builtin_amdgcn_mfma_f32_16x16x32_bf16(al[mi], bh[ni], acc[mi][ni], 0, 0, 0);
                }
        }
        __syncthreads();
    }

    #pragma unroll
    for (int ni = 0; ni < FN; ++ni) {
        int col = n0 + wn * FN * 16 + ni * 16 + lr;
        float bb = bias[col];
        #pragma unroll
        for (int mi = 0; mi < FM; ++mi) {
            #pragma unroll
            for (int r = 0; r < 4; ++r) {
                int row = m0 + wm * FM * 16 + mi * 16 + kg * 4 + r;
                C[(size_t)row * INNER + col] = acc[mi][ni][r] + bb;
            }
        }
    }
}

// ---------- step GEMM, BK=128, global_load_lds staging (validated round-14/15) ----------
template<int BM, int BN, int FM, int FN>
__global__ __launch_bounds__(256)
void step_gemm(const u16* __restrict__ Ahi, const u16* __restrict__ Alo,
               const u16* __restrict__ Bhi, const u16* __restrict__ Blo,
               float* __restrict__ C, int ldc)
{
    constexpr int NWN = BN / (FN * 16);
    constexpr int NWM = BM / (FM * 16);
    static_assert(NWM * NWN == 4, "need 4 waves");
    __shared__ char lds[(BM + BN) * 512];
    char* sAhi = lds;
    char* sAlo = lds + BM * 256;
    char* sBhi = lds + BM * 512;
    char* sBlo = lds + BM * 512 + BN * 256;

    const int tid = threadIdx.x;
    const int m0 = blockIdx.y * BM, n0 = blockIdx.x * BN;
    const int wid = tid >> 6, lane = tid & 63;
    const int wm = wid / NWN, wn = wid % NWN;
    const int lr = lane & 15, kg = lane >> 4;

    const int lrow = lane >> 4;
    const int lslot = lane & 15;

    f32x4 acc[FM][FN] = {};

    for (int k0 = 0; k0 < H; k0 += 128) {
        #pragma unroll
        for (int i = 0; i < BM / 16; ++i) {
            const int c = wid * (BM / 16) + i;
            const int r = c * 4 + lrow;
            const int swz = lslot ^ (r & 7);
            const size_t go = (size_t)(m0 + r) * H + k0 + swz * 8;
            gload_lds16(Ahi + go, sAhi + c * 1024);
            gload_lds16(Alo + go, sAlo + c * 1024);
        }
        #pragma unroll
        for (int i = 0; i < BN / 16; ++i) {
            const int c = wid * (BN / 16) + i;
            const int r = c * 4 + lrow;
            const int swz = lslot ^ (r & 7);
            const size_t go = (size_t)(n0 + r) * H + k0 + swz * 8;
            gload_lds16(Bhi + go, sBhi + c * 1024);
            gload_lds16(Blo + go, sBlo + c * 1024);
        }
        __syncthreads();

        #pragma unroll
        for (int ks = 0; ks < 4; ++ks) {
            short8 ah[FM], al[FM], bh[FN], bl[FN];
            #pragma unroll
            for (int mi = 0; mi < FM; ++mi) {
                int row = wm * FM * 16 + mi * 16 + lr;
                int off = row * 256 + ((((ks << 2) | kg) ^ (row & 7)) << 4);
                ah[mi] = *(const short8*)(sAhi + off);
                al[mi] = *(const short8*)(sAlo + off);
            }
            #pragma unroll
            for (int ni = 0; ni < FN; ++ni) {
                int row = wn * FN * 16 + ni * 16 + lr;
                int off = row * 256 + ((((ks << 2) | kg) ^ (row & 7)) << 4);
                bh[ni] = *(const short8*)(sBhi + off);
                bl[ni] = *(const short8*)(sBlo + off);
            }
            #pragma unroll
            for (int mi = 0; mi < FM; ++mi)
                #pragma unroll
                for (int ni = 0; ni < FN; ++ni) {
                    acc[mi][ni] = __builtin_amdgcn_mfma_f32_16x16x32_bf16(ah[mi], bh[ni], acc[mi][ni], 0, 0, 0);
                    acc[mi][ni] = __builtin_amdgcn_mfma_f32_16x16x32_bf16(ah[mi], bl[ni], acc[mi][ni], 0, 0, 0);
                    acc[mi][ni] = __builtin_amdgcn_mfma_f32_16x16x32_bf16(al[mi], bh[ni], acc[mi][ni], 0, 0, 0);
                }
        }
        __syncthreads();
    }

    #pragma unroll
    for (int mi = 0; mi < FM; ++mi)
        #pragma unroll
        for (int ni = 0; ni < FN; ++ni) {
            int col = n0 + wn * FN * 16 + ni * 16 + lr;
            #pragma unroll
            for (int r = 0; r < 4; ++r) {
                int row = m0 + wm * FM * 16 + mi * 16 + kg * 4 + r;
                C[(size_t)row * ldc + col] = acc[mi][ni][r];
            }
        }
}

// ---------- split-K step GEMM (G2): 32x32 tiles, grid.z = k-half (VALIDATED r16) ----------
__global__ __launch_bounds__(256)
void step_gemm_sk(const u16* __restrict__ Ahi, const u16* __restrict__ Alo,
                  const u16* __restrict__ Bhi, const u16* __restrict__ Blo,
                  float* __restrict__ Cpart, int ldc, int partStride)
{
    constexpr int BM = 32, BN = 32;
    constexpr int KSPAN = H / 2;   // 512
    __shared__ char lds[(BM + BN) * 512];
    char* sAhi = lds;
    char* sAlo = lds + BM * 256;
    char* sBhi = lds + BM * 512;
    char* sBlo = lds + BM * 512 + BN * 256;

    const int tid = threadIdx.x;
    const int m0 = blockIdx.y * BM, n0 = blockIdx.x * BN;
    const int kbeg = blockIdx.z * KSPAN;
    const int wid = tid >> 6, lane = tid & 63;
    const int wm = wid >> 1, wn = wid & 1;
    const int lr = lane & 15, kg = lane >> 4;

    const int lrow = lane >> 4;
    const int lslot = lane & 15;

    f32x4 acc = {};

    for (int k0 = kbeg; k0 < kbeg + KSPAN; k0 += 128) {
        #pragma unroll
        for (int i = 0; i < BM / 16; ++i) {
            const int c = wid * (BM / 16) + i;
            const int r = c * 4 + lrow;
            const int swz = lslot ^ (r & 7);
            const size_t go = (size_t)(m0 + r) * H + k0 + swz * 8;
            gload_lds16(Ahi + go, sAhi + c * 1024);
            gload_lds16(Alo + go, sAlo + c * 1024);
        }
        #pragma unroll
        for (int i = 0; i < BN / 16; ++i) {
            const int c = wid * (BN / 16) + i;
            const int r = c * 4 + lrow;
            const int swz = lslot ^ (r & 7);
            const size_t go = (size_t)(n0 + r) * H + k0 + swz * 8;
            gload_lds16(Bhi + go, sBhi + c * 1024);
            gload_lds16(Blo + go, sBlo + c * 1024);
        }
        __syncthreads();

        #pragma unroll
        for (int ks = 0; ks < 4; ++ks) {
            short8 ah, al, bh, bl;
            {
                int row = wm * 16 + lr;
                int off = row * 256 + ((((ks << 2) | kg) ^ (row & 7)) << 4);
                ah = *(const short8*)(sAhi + off);
                al = *(const short8*)(sAlo + off);
            }
            {
                int row = wn * 16 + lr;
                int off = row * 256 + ((((ks << 2) | kg) ^ (row & 7)) << 4);
                bh = *(const short8*)(sBhi + off);
                bl = *(const short8*)(sBlo + off);
            }
            acc = __builtin_amdgcn_mfma_f32_16x16x32_bf16(ah, bh, acc, 0, 0, 0);
            acc = __builtin_amdgcn_mfma_f32_16x16x32_bf16(ah, bl, acc, 0, 0, 0);
            acc = __builtin_amdgcn_mfma_f32_16x16x32_bf16(al, bh, acc, 0, 0, 0);
        }
        __syncthreads();
    }

    float* Cp = Cpart + (size_t)blockIdx.z * partStride;
    const int col = n0 + wn * 16 + lr;
    #pragma unroll
    for (int r = 0; r < 4; ++r) {
        int row = m0 + wm * 16 + kg * 4 + r;
        Cp[(size_t)row * ldc + col] = acc[r];
    }
}

// ---------- block reduce (sum, sumsq) over 256 threads ----------
__device__ inline void block_reduce2(float& s, float& sq, int tid) {
    #pragma unroll
    for (int off = 32; off > 0; off >>= 1) { s += __shfl_down(s, off); sq += __shfl_down(sq, off); }
    __shared__ float rs[4], rq[4];
    if ((tid & 63) == 0) { rs[tid >> 6] = s; rq[tid >> 6] = sq; }
    __syncthreads();
    s  = rs[0] + rs[1] + rs[2] + rs[3];
    sq = rq[0] + rq[1] + rq[2] + rq[3];
    __syncthreads();
}

// ---------- per-row LN stats over S1b rows of 3072 -> (mean, 1/denom) ----------
__global__ __launch_bounds__(256)
void ln_stats_v(const float* __restrict__ S1b, float* __restrict__ stat)
{
    const int row = blockIdx.x, tid = threadIdx.x;
    const float* p = S1b + (size_t)row * INNER;
    float s = 0.f, sq = 0.f;
    #pragma unroll
    for (int i = 0; i < 3; ++i) {
        float4 v = *(const float4*)(p + (tid + i * 256) * 4);
        s += v.x + v.y + v.z + v.w;
        sq += v.x*v.x + v.y*v.y + v.z*v.z + v.w*v.w;
    }
    block_reduce2(s, sq, tid);
    if (tid == 0) {
        float mean = s / (float)INNER;
        float var  = sq / (float)INNER - mean * mean;
        stat[row * 2 + 0] = mean;
        stat[row * 2 + 1] = 1.f / (sqrtf(var + EPSF) + EPSF);
    }
}

// ---------- step elementwise 1 ----------
__global__ __launch_bounds__(256)
void step_e1_v(const float* __restrict__ s2raw, const float* __restrict__ S1b,
               const float* __restrict__ stat, const float* __restrict__ h,
               const float* __restrict__ gammas, const float* __restrict__ betas,
               float* __restrict__ z, u16* __restrict__ rh_hi, u16* __restrict__ rh_lo, int t)
{
    const int b = blockIdx.x, tid = threadIdx.x;
    const float* row = s2raw + (size_t)b * NZ;
    float az[4], ar[4];
    {
        float4 vz = *(const float4*)(row + tid * 4);
        float4 vr = *(const float4*)(row + 1024 + tid * 4);
        az[0]=vz.x; az[1]=vz.y; az[2]=vz.z; az[3]=vz.w;
        ar[0]=vr.x; ar[1]=vr.y; ar[2]=vr.z; ar[3]=vr.w;
    }
    float s = 0.f, sq = 0.f;
    #pragma unroll
    for (int q = 0; q < 4; ++q) { s += az[q] + ar[q]; sq += az[q]*az[q] + ar[q]*ar[q]; }
    block_reduce2(s, sq, tid);
    const float mean = s / (float)NZ;
    const float var  = sq / (float)NZ - mean * mean;
    const float denom = sqrtf(var + EPSF) + EPSF;

    const size_t srow = (size_t)b * T + t;
    const float s1m = stat[srow * 2 + 0], s1r = stat[srow * 2 + 1];
    const float* s1 = S1b + srow * INNER;
    const int j0 = tid * 4;
    float4 zo;
    float* zp = (float*)&zo;
    #pragma unroll
    for (int q = 0; q < 4; ++q) {
        int j = j0 + q;
        float s1v = gammas[j] * (s1[j] - s1m) * s1r + betas[j];
        float ln  = gammas[INNER + j] * (az[q] - mean) / denom + betas[INNER + j];
        float sv  = 0.2f * (s1v + ln) + 0.5f;
        zp[q] = fminf(fmaxf(sv, 0.f), 1.f);
    }
    *(float4*)(z + (size_t)b * H + j0) = zo;

    uint2 hp, lp;
    u16 hh[4], ll[4];
    #pragma unroll
    for (int q = 0; q < 4; ++q) {
        int j = 1024 + j0 + q;
        float s1v = gammas[j] * (s1[j] - s1m) * s1r + betas[j];
        float ln  = gammas[INNER + j] * (ar[q] - mean) / denom + betas[INNER + j];
        float sv  = 0.2f * (s1v + ln) + 0.5f;
        sv = fminf(fmaxf(sv, 0.f), 1.f);
        float rv = sv * h[(size_t)b * H + j0 + q];
        hh[q] = f2bf(rv);
        ll[q] = f2bf(rv - bf2f(hh[q]));
    }
    hp.x = (u32)hh[0] | ((u32)hh[1] << 16); hp.y = (u32)hh[2] | ((u32)hh[3] << 16);
    lp.x = (u32)ll[0] | ((u32)ll[1] << 16); lp.y = (u32)ll[2] | ((u32)ll[3] << 16);
    *(uint2*)(rh_hi + (size_t)b * H + j0) = hp;
    *(uint2*)(rh_lo + (size_t)b * H + j0) = lp;
}

// ---------- step elementwise 2 (sums 2 split-K partials of candraw) ----------
__global__ __launch_bounds__(256)
void step_e2_v(const float* __restrict__ cand0, const float* __restrict__ cand1,
               const float* __restrict__ S1b, const float* __restrict__ stat,
               const float* __restrict__ gammas, const float* __restrict__ betas,
               const float* __restrict__ z, float* __restrict__ h,
               u16* __restrict__ h_hi, u16* __restrict__ h_lo,
               float* __restrict__ out, int t)
{
    const int b = blockIdx.x, tid = threadIdx.x;
    float a[4];
    {
        float4 v0 = *(const float4*)(cand0 + (size_t)b * H + tid * 4);
        float4 v1 = *(const float4*)(cand1 + (size_t)b * H + tid * 4);
        a[0]=v0.x+v1.x; a[1]=v0.y+v1.y; a[2]=v0.z+v1.z; a[3]=v0.w+v1.w;
    }
    float s = a[0]+a[1]+a[2]+a[3];
    float sq = a[0]*a[0]+a[1]*a[1]+a[2]*a[2]+a[3]*a[3];
    block_reduce2(s, sq, tid);
    const float mean = s / (float)H;
    const float var  = sq / (float)H - mean * mean;
    const float denom = sqrtf(var + EPSF) + EPSF;

    const size_t srow = (size_t)b * T + t;
    const float s1m = stat[srow * 2 + 0], s1r = stat[srow * 2 + 1];
    const float* s1 = S1b + srow * INNER + NZ;
    const int j0 = tid * 4;
    float4 ho;
    float* hp_ = (float*)&ho;
    u16 hh[4], ll[4];
    #pragma unroll
    for (int q = 0; q < 4; ++q) {
        int j = j0 + q;
        float s1v = gammas[NZ + j] * (s1[j] - s1m) * s1r + betas[NZ + j];
        float ln  = gammas[INNER + NZ + j] * (a[q] - mean) / denom + betas[INNER + NZ + j];
        float cand = tanhf(s1v + ln);
        float zz = z[(size_t)b * H + j];
        float hold = h[(size_t)b * H + j];
        float hn = zz * hold + (1.f - zz) * cand;
        hp_[q] = hn;
        hh[q] = f2bf(hn);
        ll[q] = f2bf(hn - bf2f(hh[q]));
    }
    *(float4*)(h + (size_t)b * H + j0) = ho;
    uint2 hpck, lpck;
    hpck.x = (u32)hh[0] | ((u32)hh[1] << 16); hpck.y = (u32)hh[2] | ((u32)hh[3] << 16);
    lpck.x = (u32)ll[0] | ((u32)ll[1] << 16); lpck.y = (u32)ll[2] | ((u32)ll[3] << 16);
    *(uint2*)(h_hi + (size_t)b * H + j0) = hpck;
    *(uint2*)(h_lo + (size_t)b * H + j0) = lpck;
    *(float4*)(out + ((size_t)b * T + t) * H + j0) = ho;
}

// ================= fallback (validated fp32 path) =================
__global__ __launch_bounds__(256)
void ln_rows_v(float* __restrict__ S1, const float* __restrict__ bias,
               const float* __restrict__ gammas, const float* __restrict__ betas)
{
    const int row = blockIdx.x, tid = threadIdx.x;
    float* p = S1 + (size_t)row * INNER;
    float a[12];
    float s = 0.f, sq = 0.f;
    #pragma unroll
    for (int i = 0; i < 3; ++i) {
        int c = tid + i * 256;
        float4 v = *(const float4*)(p + c * 4);
        float4 bb = *(const float4*)(bias + c * 4);
        a[i*4+0] = v.x + bb.x; a[i*4+1] = v.y + bb.y; a[i*4+2] = v.z + bb.z; a[i*4+3] = v.w + bb.w;
        s += a[i*4+0] + a[i*4+1] + a[i*4+2] + a[i*4+3];
        sq += a[i*4+0]*a[i*4+0] + a[i*4+1]*a[i*4+1] + a[i*4+2]*a[i*4+2] + a[i*4+3]*a[i*4+3];
    }
    block_reduce2(s, sq, tid);
    const float mean = s / (float)INNER;
    const float var  = sq / (float)INNER - mean * mean;
    const float denom = sqrtf(var + EPSF) + EPSF;
    #pragma unroll
    for (int i = 0; i < 3; ++i) {
        int c = tid + i * 256;
        float4 o;
        o.x = gammas[c*4+0] * (a[i*4+0] - mean) / denom + betas[c*4+0];
        o.y = gammas[c*4+1] * (a[i*4+1] - mean) / denom + betas[c*4+1];
        o.z = gammas[c*4+2] * (a[i*4+2] - mean) / denom + betas[c*4+2];
        o.w = gammas[c*4+3] * (a[i*4+3] - mean) / denom + betas[c*4+3];
        *(float4*)(p + c * 4) = o;
    }
}

__global__ __launch_bounds__(256)
void gemm_fb(const float* __restrict__ A, int lda,
             const float* __restrict__ Bm, int ldb,
             float* __restrict__ C, int ldc, int K)
{
    constexpr int BM = 64, BN = 64, BK = 16;
    __shared__ float As[BK][BM];
    __shared__ float Bs[BK][BN];
    const int tid = threadIdx.x;
    const int tx = tid & 15, ty = tid >> 4;
    float acc[4][4] = {};
    const float* Ab = A + (size_t)blockIdx.y * BM * lda;
    const float* Bb = Bm + (size_t)blockIdx.x * BN;
    for (int k0 = 0; k0 < K; k0 += BK) {
        #pragma unroll
        for (int i = 0; i < 4; ++i) {
            int e = tid + i * 256; int m = e >> 4, k = e & 15;
            As[k][m] = Ab[(size_t)m * lda + k0 + k];
        }
        #pragma unroll
        for (int i = 0; i < 4; ++i) {
            int e = tid + i * 256; int k = e >> 6, n = e & 63;
            Bs[k][n] = Bb[(size_t)(k0 + k) * ldb + n];
        }
        __syncthreads();
        #pragma unroll
        for (int k = 0; k < BK; ++k) {
            float av[4], bv[4];
            #pragma unroll
            for (int i = 0; i < 4; ++i) av[i] = As[k][ty * 4 + i];
            #pragma unroll
            for (int j = 0; j < 4; ++j) bv[j] = Bs[k][tx * 4 + j];
            #pragma unroll
            for (int i = 0; i < 4; ++i)
                #pragma unroll
                for (int j = 0; j < 4; ++j)
                    acc[i][j] = fmaf(av[i], bv[j], acc[i][j]);
        }
        __syncthreads();
    }
    const int row0 = blockIdx.y * BM + ty * 4;
    const int col0 = blockIdx.x * BN + tx * 4;
    #pragma unroll
    for (int i = 0; i < 4; ++i)
        #pragma unroll
        for (int j = 0; j < 4; ++j)
            C[(size_t)(row0 + i) * ldc + col0 + j] = acc[i][j];
}

__global__ __launch_bounds__(256)
void step_e1_fb(const float* __restrict__ s2raw, const float* __restrict__ S1,
                const float* __restrict__ h,
                const float* __restrict__ gammas, const float* __restrict__ betas,
                float* __restrict__ z, float* __restrict__ rh, int t)
{
    const int b = blockIdx.x, tid = threadIdx.x;
    const float* row = s2raw + (size_t)b * NZ;
    float v[8]; float s = 0.f, sq = 0.f;
    #pragma unroll
    for (int i = 0; i < 8; ++i) { v[i] = row[tid + i * 256]; s += v[i]; sq += v[i]*v[i]; }
    block_reduce2(s, sq, tid);
    const float mean = s / (float)NZ;
    const float var  = sq / (float)NZ - mean * mean;
    const float denom = sqrtf(var + EPSF) + EPSF;
    const float* s1 = S1 + (size_t)(b * T + t) * INNER;
    #pragma unroll
    for (int i = 0; i < 8; ++i) {
        int j = tid + i * 256;
        float ln = gammas[INNER + j] * (v[i] - mean) / denom + betas[INNER + j];
        float sv = 0.2f * (s1[j] + ln) + 0.5f;
        sv = fminf(fmaxf(sv, 0.f), 1.f);
        if (j < H) z[(size_t)b * H + j] = sv;
        else       rh[(size_t)b * H + (j - H)] = sv * h[(size_t)b * H + (j - H)];
    }
}

__global__ __launch_bounds__(256)
void step_e2_fb(const float* __restrict__ candraw, const float* __restrict__ S1,
                const float* __restrict__ gammas, const float* __restrict__ betas,
                const float* __restrict__ z, float* __restrict__ h,
                float* __restrict__ out, int t)
{
    const int b = blockIdx.x, tid = threadIdx.x;
    float v[4]; float s = 0.f, sq = 0.f;
    #pragma unroll
    for (int i = 0; i < 4; ++i) { v[i] = candraw[(size_t)b * H + tid + i * 256]; s += v[i]; sq += v[i]*v[i]; }
    block_reduce2(s, sq, tid);
    const float mean = s / (float)H;
    const float var  = sq / (float)H - mean * mean;
    const float denom = sqrtf(var + EPSF) + EPSF;
    const float* s1 = S1 + (size_t)(b * T + t) * INNER + NZ;
    #pragma unroll
    for (int i = 0; i < 4; ++i) {
        int j = tid + i * 256;
        float ln = gammas[INNER + NZ + j] * (v[i] - mean) / denom + betas[INNER + NZ + j];
        float cand = tanhf(s1[j] + ln);
        float zz = z[(size_t)b * H + j];
        float hold = h[(size_t)b * H + j];
        float hn = zz * hold + (1.f - zz) * cand;
        h[(size_t)b * H + j] = hn;
        out[((size_t)b * T + t) * H + j] = hn;
    }
}

// ================= launch =================
extern "C" void kernel_launch(void* const* d_in, const int* in_sizes, int n_in,
                              void* d_out, int out_size, void* d_ws, size_t ws_size,
                              hipStream_t stream) {
    const float* x      = (const float*)d_in[0];
    const float* W      = (const float*)d_in[1];
    const float* U      = (const float*)d_in[2];
    const float* bias   = (const float*)d_in[3];
    const float* gammas = (const float*)d_in[4];
    const float* betas  = (const float*)d_in[5];
    float* out = (float*)d_out;
    (void)in_sizes; (void)n_in; (void)out_size;

    char* ws = (char*)d_ws;
    size_t off = 0;
    auto alloc = [&](size_t bytes) { void* p = ws + off; off += (bytes + 255) & ~(size_t)255; return p; };

    const size_t sz_S1 = (size_t)BT * INNER * 4;          // 402.7 MB
    const size_t sz_T  = (size_t)INNER * H * 2;           // 6.29 MB per split half
    const size_t sz_st = (size_t)BT * 2 * 4;              // 256 KB
    constexpr int CHUNK = 8192;
    const size_t sz_xc = (size_t)CHUNK * H * 2;           // 16 MB per split half
    const size_t sz_small = ((size_t)B * H * 4) * 4 + (size_t)B * NZ * 4
                          + ((size_t)B * H * 2) * 4 + 16 * 1024;
    const size_t need_r9 = sz_S1 + 4 * sz_T + sz_st + sz_small;   // ~436.5 MB
    const size_t need_gl = need_r9 + 2 * sz_xc;                   // ~468.5 MB

    if (ws_size >= need_r9) {
        float* S1b   = (float*)alloc(sz_S1);
        u16* WT_hi   = (u16*)alloc(sz_T);
        u16* WT_lo   = (u16*)alloc(sz_T);
        u16* UT_hi   = (u16*)alloc(sz_T);
        u16* UT_lo   = (u16*)alloc(sz_T);
        float* stat  = (float*)alloc(sz_st);
        float* h     = (float*)alloc((size_t)B * H * 4);
        float* z     = (float*)alloc((size_t)B * H * 4);
        float* s2raw = (float*)alloc((size_t)B * NZ * 4);
        float* cand2 = (float*)alloc((size_t)B * H * 4 * 2);   // 2 split-K partials
        u16* h_hi    = (u16*)alloc((size_t)B * H * 2);
        u16* h_lo    = (u16*)alloc((size_t)B * H * 2);
        u16* rh_hi   = (u16*)alloc((size_t)B * H * 2);
        u16* rh_lo   = (u16*)alloc((size_t)B * H * 2);

        transpose_split<<<dim3(INNER / 32, H / 32), 256, 0, stream>>>(W, WT_hi, WT_lo);
        transpose_split<<<dim3(INNER / 32, H / 32), 256, 0, stream>>>(U, UT_hi, UT_lo);

        if (ws_size >= need_gl) {
            u16* x_hi = (u16*)alloc(sz_xc);
            u16* x_lo = (u16*)alloc(sz_xc);
            for (int c0 = 0; c0 < BT; c0 += CHUNK) {
                split_f32<<<(CHUNK * H / 4) / 256, 256, 0, stream>>>(
                    x + (size_t)c0 * H, x_hi, x_lo);
                gemm_s1gl<<<dim3(INNER / 128, CHUNK / 128), 256, 0, stream>>>(
                    x_hi, x_lo, WT_hi, WT_lo, bias, S1b + (size_t)c0 * INNER);
            }
        } else {
            gemm_s1<<<dim3(INNER / 128, BT / 128), 256, 0, stream>>>(x, WT_hi, WT_lo, bias, S1b);
        }
        ln_stats_v<<<BT, 256, 0, stream>>>(S1b, stat);

        hipMemsetAsync(h,    0, (size_t)B * H * 4, stream);
        hipMemsetAsync(h_hi, 0, (size_t)B * H * 2, stream);
        hipMemsetAsync(h_lo, 0, (size_t)B * H * 2, stream);

        const u16* Uc_hi = UT_hi + (size_t)NZ * H;
        const u16* Uc_lo = UT_lo + (size_t)NZ * H;

        for (int t = 0; t < T; ++t) {
            // G1: 16x64 tiles -> 512 blocks = 2 blocks/CU (validated round-15/16)
            step_gemm<16, 64, 1, 1><<<dim3(NZ / 64, B / 16), 256, 0, stream>>>(
                h_hi, h_lo, UT_hi, UT_lo, s2raw, NZ);
            step_e1_v<<<B, 256, 0, stream>>>(s2raw, S1b, stat, h, gammas, betas,
                                             z, rh_hi, rh_lo, t);
            // G2: 32x32 tiles, split-K=2 -> 512 blocks (validated round-16)
            step_gemm_sk<<<dim3(H / 32, B / 32, 2), 256, 0, stream>>>(
                rh_hi, rh_lo, Uc_hi, Uc_lo, cand2, H, B * H);
            step_e2_v<<<B, 256, 0, stream>>>(cand2, cand2 + (size_t)B * H, S1b, stat,
                                             gammas, betas, z, h, h_hi, h_lo, out, t);
        }
    } else {
        // fallback: validated fp32 path
        float* S1    = (float*)alloc(sz_S1);
        float* h     = (float*)alloc((size_t)B * H * 4);
        float* z     = (float*)alloc((size_t)B * H * 4);
        float* rh    = (float*)alloc((size_t)B * H * 4);
        float* s2raw = (float*)alloc((size_t)B * NZ * 4);
        float* candraw = (float*)alloc((size_t)B * H * 4);

        hipMemsetAsync(h, 0, (size_t)B * H * 4, stream);
        gemm_fb<<<dim3(INNER / 64, BT / 64), 256, 0, stream>>>(x, H, W, INNER, S1, INNER, H);
        ln_rows_v<<<BT, 256, 0, stream>>>(S1, bias, gammas, betas);
        for (int t = 0; t < T; ++t) {
            gemm_fb<<<dim3(NZ / 64, B / 64), 256, 0, stream>>>(h, H, U, INNER, s2raw, NZ, H);
            step_e1_fb<<<B, 256, 0, stream>>>(s2raw, S1, h, gammas, betas, z, rh, t);
            gemm_fb<<<dim3(H / 64, B / 64), 256, 0, stream>>>(rh, H, U + NZ, INNER, candraw, H, H);
            step_e2_fb<<<B, 256, 0, stream>>>(candraw, S1, gammas, betas, z, h, out, t);
        }
    }
}